// Round 4
// baseline (1271.937 us; speedup 1.0000x reference)
//
#include <hip/hip_runtime.h>

#define BB 8
#define IC 32
#define OC 64
#define HH 256
#define WW 256
#define EPS 1e-5f

typedef __attribute__((ext_vector_type(8))) short bf16x8;
typedef __attribute__((ext_vector_type(4))) float f32x4;

#define XSTR 40   // xs per-pixel stride in shorts (32 ic + 8 pad, 16B-aligned frags)
#define YSTR 40   // ys per-pixel stride in shorts (32 ic + 8 pad)
#define NT4  4224 // 22 rows * 32 ic * 6 float4 per tile-window

// ---- workspace layout (float indices) ----
#define WS_GAP   0                      // 256
#define WS_BIDX  256                    // 8 ints
#define WS_W1F   264                    // 18432 bf16 = 9216 floats (conv1 A-frags)
#define WS_B1F   (WS_W1F + 9216)        // 64
#define WS_W2F   (WS_B1F + 64)          // 102400 bf16 = 51200 floats (conv2 A-frags)
#define WS_B2F   (WS_W2F + 51200)       // 64
#define WS_SXWT  (WS_B2F + 64)          // 51200 (fp32 [ic][k][oc], edge branch)
#define WS_SXBF  (WS_SXWT + 51200)      // 64
#define WS_SYWT  (WS_SXBF + 64)         // 51200
#define WS_SYBF  (WS_SYWT + 51200)      // 64
#define WS_LWT   (WS_SYBF + 64)         // 51200
#define WS_LBF   (WS_LWT + 51200)       // 64

__device__ inline unsigned short bf16r(float f) {
    unsigned int u = __float_as_uint(f);
    unsigned int r = (u + 0x7fffu + ((u >> 16) & 1u)) >> 16;
    return (unsigned short)r;
}

// ------------------------------------------------------------------
// prep: fold BN scales into weights; conv1/conv2 weights emitted as bf16
// MFMA A-fragments (lane-major, 16B per lane, contiguous).
// ------------------------------------------------------------------
__global__ void prep_kernel(const float* __restrict__ mw1, const float* __restrict__ mb1, const float* __restrict__ mbn1,
                            const float* __restrict__ mw2, const float* __restrict__ mb2, const float* __restrict__ mbn2,
                            const float* __restrict__ sxw, const float* __restrict__ sxb, const float* __restrict__ sxbn,
                            const float* __restrict__ syw, const float* __restrict__ syb, const float* __restrict__ sybn,
                            const float* __restrict__ lw,  const float* __restrict__ lb,  const float* __restrict__ lbn,
                            float* __restrict__ ws) {
    int idx = blockIdx.x * 256 + threadIdx.x;

    if (idx < 18432) {  // conv1 A-frags
        int j = idx & 7, lane = (idx >> 3) & 63, oct = (idx >> 9) & 1, ht = idx >> 10;
        int t = ht % 9, h = ht / 9;
        int oc = h * 32 + oct * 16 + (lane & 15);
        int ic = (lane >> 4) * 8 + j;
        float s = mbn1[oc] * rsqrtf(mbn1[192 + oc] + EPS);
        ((unsigned short*)(ws + WS_W1F))[idx] = bf16r(mw1[(oc * IC + ic) * 9 + t] * s);
    }
    if (idx < 102400) {  // conv2 A-frags
        int j = idx & 7, lane = (idx >> 3) & 63, oct = (idx >> 9) & 3, ht = idx >> 11;
        int t = ht % 25, h = ht / 25;
        int oc = oct * 16 + (lane & 15);
        int ic = h * 32 + (lane >> 4) * 8 + j;
        float s = mbn2[oc] * rsqrtf(mbn2[192 + oc] + EPS);
        ((unsigned short*)(ws + WS_W2F))[idx] = bf16r(mw2[(oc * OC + ic) * 25 + t] * s);
    }
    if (idx < 51200) {  // edge-branch fp32 transposed weights [ic][k][oc]
        int oc = idx & 63, k = (idx >> 6) % 25, ic = idx / (25 * 64);
        float ssx = sxbn[oc] * rsqrtf(sxbn[192 + oc] + EPS);
        float ssy = sybn[oc] * rsqrtf(sybn[192 + oc] + EPS);
        float sl  = lbn[oc]  * rsqrtf(lbn[192 + oc]  + EPS);
        ws[WS_SXWT + idx] = sxw[(oc * IC + ic) * 25 + k] * ssx;
        ws[WS_SYWT + idx] = syw[(oc * IC + ic) * 25 + k] * ssy;
        ws[WS_LWT  + idx] = lw [(oc * IC + ic) * 25 + k] * sl;
    }
    if (idx < 64) {
        float s1 = mbn1[idx] * rsqrtf(mbn1[192 + idx] + EPS);
        ws[WS_B1F + idx] = (mb1[idx] - mbn1[128 + idx]) * s1 + mbn1[64 + idx];
        float s2 = mbn2[idx] * rsqrtf(mbn2[192 + idx] + EPS);
        ws[WS_B2F + idx] = (mb2[idx] - mbn2[128 + idx]) * s2 + mbn2[64 + idx];
        float sx = sxbn[idx] * rsqrtf(sxbn[192 + idx] + EPS);
        ws[WS_SXBF + idx] = (sxb[idx] - sxbn[128 + idx]) * sx + sxbn[64 + idx];
        float sy = sybn[idx] * rsqrtf(sybn[192 + idx] + EPS);
        ws[WS_SYBF + idx] = (syb[idx] - sybn[128 + idx]) * sy + sybn[64 + idx];
        float sl = lbn[idx] * rsqrtf(lbn[192 + idx] + EPS);
        ws[WS_LBF + idx] = (lb[idx] - lbn[128 + idx]) * sl + lbn[64 + idx];
    }
}

// ------------------------------------------------------------------
__global__ void gap_kernel(const float* __restrict__ x, float* __restrict__ ws) {
    int bc = blockIdx.x;
    const float4* p = (const float4*)(x + (size_t)bc * (HH * WW));
    float s = 0.f;
    for (int i = threadIdx.x; i < (HH * WW) / 4; i += 256) {
        float4 v = p[i];
        s += (v.x + v.y) + (v.z + v.w);
    }
    #pragma unroll
    for (int off = 32; off; off >>= 1) s += __shfl_down(s, off, 64);
    __shared__ float red[4];
    int lane = threadIdx.x & 63, w = threadIdx.x >> 6;
    if (lane == 0) red[w] = s;
    __syncthreads();
    if (threadIdx.x == 0)
        ws[WS_GAP + bc] = (red[0] + red[1] + red[2] + red[3]) * (1.f / (HH * WW));
}

__global__ void gate_kernel(const float* __restrict__ w1, const float* __restrict__ b1,
                            const float* __restrict__ gbn,
                            const float* __restrict__ w2, const float* __restrict__ b2,
                            float* __restrict__ ws) {
    __shared__ float hsh[8][32];
    int tid = threadIdx.x;
    int b = tid >> 5, j = tid & 31;
    float acc = b1[j];
    for (int i = 0; i < 32; i++) acc += ws[WS_GAP + b * 32 + i] * w1[j * 32 + i];
    float s = gbn[j] * rsqrtf(gbn[96 + j] + EPS);
    hsh[b][j] = tanhf((acc - gbn[64 + j]) * s + gbn[32 + j]);
    __syncthreads();
    if (tid < 8) {
        float best = -1e30f; int bi = 0;
        for (int c = 0; c < 3; c++) {
            float k = b2[c];
            for (int jj = 0; jj < 32; jj++) k += hsh[tid][jj] * w2[c * 32 + jj];
            if (k > best) { best = k; bi = c; }
        }
        ((int*)ws)[WS_BIDX + tid] = bi;
    }
}

// ------------------------------------------------------------------
// Prefetch helpers: x window for tile (ty, tx) = rows ty-3..ty+18,
// cols tx-4..tx+19 (24 floats = 6 aligned float4; tx%16==0 so tx-4 is
// 16B-aligned and every float4 is fully in- or out-of-image).
// u = tid + k*256 -> c4 = u%6, ic = (u/6)%32, row = u/192.
// ------------------------------------------------------------------
__device__ __forceinline__ void pf_load_range(const float* __restrict__ xb, int ty, int tx,
                                              int tid, int k0, int k1, float4* pf) {
    #pragma unroll
    for (int k = k0; k < k1; k++) {
        int u = tid + k * 256;
        if (u < NT4) {
            int c4 = u % 6, icr = (u / 6) % 32, row = u / 192;
            int gy = ty - 3 + row, gxb = tx - 4 + c4 * 4;
            bool valid = ((unsigned)gy < HH) && ((unsigned)gxb < WW);
            size_t off = valid ? ((size_t)icr * (HH * WW) + gy * WW + gxb) : 0;
            pf[k - k0] = *(const float4*)(xb + off);
        }
    }
}

__device__ __forceinline__ void xs_write_range(short* __restrict__ xs, int ty, int tx,
                                               int tid, int k0, int k1, const float4* pf) {
    #pragma unroll
    for (int k = k0; k < k1; k++) {
        int u = tid + k * 256;
        if (u < NT4) {
            int c4 = u % 6, icr = (u / 6) % 32, row = u / 192;
            int gy = ty - 3 + row, gxb = tx - 4 + c4 * 4;
            bool valid = ((unsigned)gy < HH) && ((unsigned)gxb < WW);
            float4 v = pf[k - k0];
            float e0 = valid ? v.x : 0.f, e1 = valid ? v.y : 0.f;
            float e2 = valid ? v.z : 0.f, e3 = valid ? v.w : 0.f;
            int ccb = c4 * 4 - 1;  // xs col of element 0 (cc in [-1,22])
            short* base = xs + (row * 22) * XSTR + icr;
            if (c4 != 0) base[(ccb + 0) * XSTR] = (short)bf16r(e0);
            base[(ccb + 1) * XSTR] = (short)bf16r(e1);
            base[(ccb + 2) * XSTR] = (short)bf16r(e2);
            if (c4 != 5) base[(ccb + 3) * XSTR] = (short)bf16r(e3);
        }
    }
}

// ------------------------------------------------------------------
// main branch: fused conv3x3+bn+relu -> conv5x5+bn+relu via bf16 MFMA.
// R4: each block processes 4 adjacent 16x16 tiles (grid 64 x 8, 2 blk/CU)
// with cross-tile software pipelining: tile t+1's x window is prefetched
// into registers during tile t's conv2 phases (pure-MFMA, ~15k cyc) and
// written to xs after the last xs-reader barrier. Prefetch split in two
// halves (32+36 VGPR) to cap peak register pressure.
//   xs: [22x22 px][32 ic] bf16, stride 40  (38720 B)
//   ys: [20x20 px][32 half-ch] bf16, stride 40 (32000 B)  -> 70.7 KB
// MFMA 16x16x32 layouts (m89): A[m=lane&15][k=quad*8+j],
// B[k=quad*8+j][n=lane&15], D: col=lane&15, row=quad*4+reg.
// ------------------------------------------------------------------
__global__ void __launch_bounds__(256, 2)
main_kernel(const float* __restrict__ x, const float* __restrict__ ws, float* __restrict__ out) {
    __shared__ __align__(16) short xs[484 * XSTR];
    __shared__ __align__(16) short ys[400 * YSTR];

    int b = blockIdx.y;
    if (((const int*)ws)[WS_BIDX + b] != 0) return;
    int q = blockIdx.x;              // 64 blocks: row = q>>2 (16), colgroup = q&3 (4)
    int ty  = (q >> 2) * 16;
    int tx0 = (q & 3) * 64;
    int tid = threadIdx.x;
    int w = tid >> 6, lane = tid & 63, n = lane & 15, quad = lane >> 4;

    const float* xb = x + (size_t)b * IC * HH * WW;
    const short* w1v = (const short*)(ws + WS_W1F);
    const bf16x8* w2v = (const bf16x8*)(ws + WS_W2F);

    float4 pfA[8], pfB[9];

    // ---- stage tile 0 directly ----
    pf_load_range(xb, ty, tx0, tid, 0, 8, pfA);
    pf_load_range(xb, ty, tx0, tid, 8, 17, pfB);
    xs_write_range(xs, ty, tx0, tid, 0, 8, pfA);
    xs_write_range(xs, ty, tx0, tid, 8, 17, pfB);
    __syncthreads();

    int mrow0 = w * 4;   // conv2 output rows of this wave
    int yr0   = w * 5;   // conv1 output rows of this wave

    #pragma unroll 1
    for (int t = 0; t < 4; t++) {
        int tx = tx0 + t * 16;

        f32x4 acc2[4][4];
        #pragma unroll
        for (int i = 0; i < 4; i++)
            #pragma unroll
            for (int jj = 0; jj < 4; jj++) acc2[i][jj] = (f32x4){0.f, 0.f, 0.f, 0.f};

        #pragma unroll
        for (int h = 0; h < 2; h++) {
            // ---- conv1 half h: Y[20x20][32] for conv1 oc = h*32..h*32+31 ----
            #pragma unroll
            for (int cg = 0; cg < 2; cg++) {
                int cb = cg * 4;
                f32x4 a1[5][2];
                #pragma unroll
                for (int rr = 0; rr < 5; rr++) {
                    a1[rr][0] = (f32x4){0.f, 0.f, 0.f, 0.f};
                    a1[rr][1] = (f32x4){0.f, 0.f, 0.f, 0.f};
                }
                #pragma unroll
                for (int dw = 0; dw < 3; dw++) {
                    bf16x8 w1f[3][2];
                    #pragma unroll
                    for (int dh = 0; dh < 3; dh++) {
                        int tt = dh * 3 + dw;
                        w1f[dh][0] = *(const bf16x8*)(w1v + (((h * 9 + tt) * 2 + 0) * 64 + lane) * 8);
                        w1f[dh][1] = *(const bf16x8*)(w1v + (((h * 9 + tt) * 2 + 1) * 64 + lane) * 8);
                    }
                    bf16x8 bfr[7];
                    #pragma unroll
                    for (int rI = 0; rI < 7; rI++)
                        bfr[rI] = *(const bf16x8*)(xs + ((yr0 + rI) * 22 + cb + n + dw) * XSTR + quad * 8);
                    #pragma unroll
                    for (int dh = 0; dh < 3; dh++)
                        #pragma unroll
                        for (int rr = 0; rr < 5; rr++) {
                            a1[rr][0] = __builtin_amdgcn_mfma_f32_16x16x32_bf16(w1f[dh][0], bfr[rr + dh], a1[rr][0], 0, 0, 0);
                            a1[rr][1] = __builtin_amdgcn_mfma_f32_16x16x32_bf16(w1f[dh][1], bfr[rr + dh], a1[rr][1], 0, 0, 0);
                        }
                }
                #pragma unroll
                for (int oct = 0; oct < 2; oct++) {
                    float bias1[4];
                    #pragma unroll
                    for (int r = 0; r < 4; r++)
                        bias1[r] = ws[WS_B1F + h * 32 + oct * 16 + quad * 4 + r];
                    #pragma unroll
                    for (int rr = 0; rr < 5; rr++) {
                        int yr = yr0 + rr;
                        int gy2 = ty - 2 + yr, gx2 = tx - 2 + cb + n;
                        bool inb = ((unsigned)gy2 < HH) && ((unsigned)gx2 < WW);
                        float v0 = inb ? fmaxf(a1[rr][oct][0] + bias1[0], 0.f) : 0.f;
                        float v1 = inb ? fmaxf(a1[rr][oct][1] + bias1[1], 0.f) : 0.f;
                        float v2 = inb ? fmaxf(a1[rr][oct][2] + bias1[2], 0.f) : 0.f;
                        float v3 = inb ? fmaxf(a1[rr][oct][3] + bias1[3], 0.f) : 0.f;
                        uint2 pk;
                        pk.x = (unsigned int)bf16r(v0) | ((unsigned int)bf16r(v1) << 16);
                        pk.y = (unsigned int)bf16r(v2) | ((unsigned int)bf16r(v3) << 16);
                        *(uint2*)(ys + (yr * 20 + cb + n) * YSTR + oct * 16 + quad * 4) = pk;
                    }
                }
            }
            __syncthreads();   // ys ready for conv2

            // issue prefetch for next tile during the MFMA-heavy conv2 phase
            if (t < 3) {
                if (h == 0) pf_load_range(xb, ty, tx + 16, tid, 0, 8, pfA);
                else        pf_load_range(xb, ty, tx + 16, tid, 8, 17, pfB);
            }

            // ---- conv2 partial: K-step = this half's 32 channels, 25 taps ----
            const bf16x8* w2h = w2v + (size_t)h * 100 * 64;
            bf16x8 af[4];
            {
                int base = lane;   // k=0 -> t=0
                af[0] = w2h[base]; af[1] = w2h[base + 64]; af[2] = w2h[base + 128]; af[3] = w2h[base + 192];
            }
            bf16x8 bfr2[8];
            #pragma unroll
            for (int k = 0; k < 25; k++) {
                int dw = k / 5, dh = k % 5;
                if (dh == 0) {
                    #pragma unroll
                    for (int rI = 0; rI < 8; rI++)
                        bfr2[rI] = *(const bf16x8*)(ys + ((mrow0 + rI) * 20 + n + dw) * YSTR + quad * 8);
                }
                bf16x8 an[4];
                if (k < 24) {
                    int kk = k + 1;
                    int tn = (kk % 5) * 5 + (kk / 5);
                    int base = tn * 4 * 64 + lane;
                    an[0] = w2h[base]; an[1] = w2h[base + 64]; an[2] = w2h[base + 128]; an[3] = w2h[base + 192];
                }
                #pragma unroll
                for (int r4 = 0; r4 < 4; r4++) {
                    bf16x8 bb = bfr2[r4 + dh];
                    acc2[r4][0] = __builtin_amdgcn_mfma_f32_16x16x32_bf16(af[0], bb, acc2[r4][0], 0, 0, 0);
                    acc2[r4][1] = __builtin_amdgcn_mfma_f32_16x16x32_bf16(af[1], bb, acc2[r4][1], 0, 0, 0);
                    acc2[r4][2] = __builtin_amdgcn_mfma_f32_16x16x32_bf16(af[2], bb, acc2[r4][2], 0, 0, 0);
                    acc2[r4][3] = __builtin_amdgcn_mfma_f32_16x16x32_bf16(af[3], bb, acc2[r4][3], 0, 0, 0);
                }
                af[0] = an[0]; af[1] = an[1]; af[2] = an[2]; af[3] = an[3];
            }
            if (h == 0) __syncthreads();   // ys rewrite in conv1-h1
        }

        // ---- epilogue: relu(acc + b2f), store tile t ----
        {
            float bias2[4][4];
            #pragma unroll
            for (int oct = 0; oct < 4; oct++)
                #pragma unroll
                for (int r = 0; r < 4; r++)
                    bias2[oct][r] = ws[WS_B2F + oct * 16 + quad * 4 + r];

            float* ob = out + (size_t)b * OC * HH * WW;
            #pragma unroll
            for (int r4 = 0; r4 < 4; r4++) {
                int orow = mrow0 + r4;
                #pragma unroll
                for (int oct = 0; oct < 4; oct++) {
                    #pragma unroll
                    for (int r = 0; r < 4; r++) {
                        int oc = oct * 16 + quad * 4 + r;
                        float v = fmaxf(acc2[r4][oct][r] + bias2[oct][r], 0.f);
                        ob[(size_t)oc * (HH * WW) + (ty + orow) * WW + tx + n] = v;
                    }
                }
            }
        }

        // ---- write next tile's xs (xs readers finished at the conv1-h1
        //      barrier; other waves may still be in conv2-h1 but only read ys) ----
        if (t < 3) {
            xs_write_range(xs, ty, tx + 16, tid, 0, 8, pfA);
            xs_write_range(xs, ty, tx + 16, tid, 8, 17, pfB);
        }
        __syncthreads();   // xs/ys ready for next tile's conv1
    }
}

// ------------------------------------------------------------------
// edge branches (fp32; early-exit — not selected by this seed's gate)
// ------------------------------------------------------------------
template <int KID>
__global__ void __launch_bounds__(256, 2)
edge_kernel(const float* __restrict__ x, const float* __restrict__ ws, float* __restrict__ out,
            int want, float scale, int accumulate, int wt_off, int bf_off) {
    constexpr float KSX[9] = {1, 0, -1, 2, 0, -2, 1, 0, -1};
    constexpr float KSY[9] = {1, 2, 1, 0, 0, 0, -1, -2, -1};
    constexpr float KLP[9] = {0, 1, 0, 1, -4, 1, 0, 1, 0};

    __shared__ float xsf[8 * 484];
    __shared__ float ysf[8 * 400];
    int b = blockIdx.y;
    if (((const int*)ws)[WS_BIDX + b] != want) return;
    int tile = blockIdx.x;
    int ty = (tile >> 4) * 16, tx = (tile & 15) * 16;
    int tid = threadIdx.x;

    const float* xb = x + (size_t)b * IC * HH * WW;
    const float* wt = ws + wt_off;
    const float* bf = ws + bf_off;

    float acc[8][8];
    #pragma unroll
    for (int o = 0; o < 8; o++)
        #pragma unroll
        for (int j = 0; j < 8; j++) acc[o][j] = 0.f;

    int ocg = tid >> 5;
    int ps  = tid & 31;
    int row = ps >> 1, c0 = (ps & 1) * 8;

    for (int icc = 0; icc < 4; icc++) {
        if (icc) __syncthreads();
        for (int i = tid; i < 8 * 484; i += 256) {
            int ch = i / 484, rem = i % 484, rr = rem / 22, cc = rem % 22;
            int ic = icc * 8 + ch;
            int gy = ty - 3 + rr, gx = tx - 3 + cc;
            float v = 0.f;
            if ((unsigned)gy < HH && (unsigned)gx < WW) v = xb[(size_t)ic * HH * WW + gy * WW + gx];
            xsf[i] = v;
        }
        __syncthreads();
        for (int p = tid; p < 400; p += 256) {
            int r = p / 20, c = p % 20;
            bool inb = ((unsigned)(ty - 2 + r) < HH) && ((unsigned)(tx - 2 + c) < WW);
            #pragma unroll
            for (int ch = 0; ch < 8; ch++) {
                const float* xp = xsf + ch * 484 + r * 22 + c;
                float v = 0.f;
                #pragma unroll
                for (int k = 0; k < 9; k++) {
                    float kv = (KID == 0) ? KSX[k] : (KID == 1) ? KSY[k] : KLP[k];
                    if (kv != 0.f) v += kv * xp[(k / 3) * 22 + (k % 3)];
                }
                ysf[ch * 400 + p] = inb ? v : 0.f;
            }
        }
        __syncthreads();
        for (int ic8 = 0; ic8 < 8; ic8++) {
            const float* yc = ysf + ic8 * 400;
            const float* wbase = wt + ((icc * 8 + ic8) * 25) * 64 + ocg * 8;
            #pragma unroll
            for (int dh = 0; dh < 5; dh++) {
                #pragma unroll
                for (int dw = 0; dw < 5; dw++) {
                    const float* yp = yc + (row + dh) * 20 + c0 + dw;
                    float yv[8];
                    #pragma unroll
                    for (int j = 0; j < 8; j++) yv[j] = yp[j];
                    const float4* wp = (const float4*)(wbase + (dh * 5 + dw) * 64);
                    float4 wa = wp[0], wb = wp[1];
                    float wr[8] = {wa.x, wa.y, wa.z, wa.w, wb.x, wb.y, wb.z, wb.w};
                    #pragma unroll
                    for (int o = 0; o < 8; o++)
                        #pragma unroll
                        for (int j = 0; j < 8; j++) acc[o][j] += wr[o] * yv[j];
                }
            }
        }
    }
    float* ob = out + (size_t)b * OC * HH * WW;
    #pragma unroll
    for (int o = 0; o < 8; o++) {
        int oc = ocg * 8 + o;
        float bb = bf[oc];
        float* op = ob + (size_t)oc * HH * WW + (ty + row) * WW + tx + c0;
        if (accumulate) {
            #pragma unroll
            for (int j = 0; j < 8; j++) op[j] += scale * fmaxf(acc[o][j] + bb, 0.f);
        } else {
            #pragma unroll
            for (int j = 0; j < 8; j++) op[j] = scale * fmaxf(acc[o][j] + bb, 0.f);
        }
    }
}

// ------------------------------------------------------------------
extern "C" void kernel_launch(void* const* d_in, const int* in_sizes, int n_in,
                              void* d_out, int out_size, void* d_ws, size_t ws_size,
                              hipStream_t stream) {
    const float* x    = (const float*)d_in[0];
    const float* gw1  = (const float*)d_in[1];
    const float* gb1  = (const float*)d_in[2];
    const float* gbn  = (const float*)d_in[3];
    const float* gw2  = (const float*)d_in[4];
    const float* gb2  = (const float*)d_in[5];
    const float* mw1  = (const float*)d_in[6];
    const float* mb1  = (const float*)d_in[7];
    const float* mbn1 = (const float*)d_in[8];
    const float* mw2  = (const float*)d_in[9];
    const float* mb2  = (const float*)d_in[10];
    const float* mbn2 = (const float*)d_in[11];
    const float* sxw  = (const float*)d_in[12];
    const float* sxb  = (const float*)d_in[13];
    const float* sxbn = (const float*)d_in[14];
    const float* syw  = (const float*)d_in[15];
    const float* syb  = (const float*)d_in[16];
    const float* sybn = (const float*)d_in[17];
    const float* lw   = (const float*)d_in[18];
    const float* lb   = (const float*)d_in[19];
    const float* lbn  = (const float*)d_in[20];
    float* ws  = (float*)d_ws;
    float* out = (float*)d_out;

    prep_kernel<<<400, 256, 0, stream>>>(mw1, mb1, mbn1, mw2, mb2, mbn2,
                                         sxw, sxb, sxbn, syw, syb, sybn, lw, lb, lbn, ws);
    gap_kernel<<<256, 256, 0, stream>>>(x, ws);
    gate_kernel<<<1, 256, 0, stream>>>(gw1, gb1, gbn, gw2, gb2, ws);

    dim3 grid_main(64, BB);
    main_kernel<<<grid_main, 256, 0, stream>>>(x, ws, out);
    dim3 grid(256, BB);
    edge_kernel<0><<<grid, 256, 0, stream>>>(x, ws, out, 1, 0.5f, 0, WS_SXWT, WS_SXBF);
    edge_kernel<1><<<grid, 256, 0, stream>>>(x, ws, out, 1, 0.5f, 1, WS_SYWT, WS_SYBF);
    edge_kernel<2><<<grid, 256, 0, stream>>>(x, ws, out, 2, 1.0f, 0, WS_LWT, WS_LBF);
}

// Round 5
// 518.429 us; speedup vs baseline: 2.4534x; 2.4534x over previous
//
#include <hip/hip_runtime.h>

#define BB 8
#define IC 32
#define OC 64
#define HH 256
#define WW 256
#define EPS 1e-5f

typedef __attribute__((ext_vector_type(8))) short bf16x8;
typedef __attribute__((ext_vector_type(4))) float f32x4;

#define YSTR 40     // ys per-pixel stride in shorts (32 ch + 8 pad, 16B-aligned frags)
#define XROW 1024   // xs row stride in shorts: 32 cols x 32 shorts (swizzled, no pad)

// ---- workspace layout (float indices) ----
#define WS_GAP   0                      // 256
#define WS_BIDX  256                    // 8 ints
#define WS_W1F   264                    // 18432 bf16 = 9216 floats (conv1 A-frags)
#define WS_B1F   (WS_W1F + 9216)        // 64
#define WS_W2F   (WS_B1F + 64)          // 102400 bf16 = 51200 floats (conv2 A-frags)
#define WS_B2F   (WS_W2F + 51200)       // 64
#define WS_SXWT  (WS_B2F + 64)          // 51200 (fp32 [ic][k][oc], edge branch)
#define WS_SXBF  (WS_SXWT + 51200)      // 64
#define WS_SYWT  (WS_SXBF + 64)         // 51200
#define WS_SYBF  (WS_SYWT + 51200)      // 64
#define WS_LWT   (WS_SYBF + 64)         // 51200
#define WS_LBF   (WS_LWT + 51200)       // 64

__device__ inline unsigned short bf16r(float f) {
    unsigned int u = __float_as_uint(f);
    unsigned int r = (u + 0x7fffu + ((u >> 16) & 1u)) >> 16;
    return (unsigned short)r;
}

// ------------------------------------------------------------------
// prep (blocks 0..399): fold BN into weights, emit bf16 MFMA A-frags.
// gap (blocks 400..655): per (b,c) mean of x.
// ------------------------------------------------------------------
__global__ void prep_gap_kernel(const float* __restrict__ mw1, const float* __restrict__ mb1, const float* __restrict__ mbn1,
                                const float* __restrict__ mw2, const float* __restrict__ mb2, const float* __restrict__ mbn2,
                                const float* __restrict__ sxw, const float* __restrict__ sxb, const float* __restrict__ sxbn,
                                const float* __restrict__ syw, const float* __restrict__ syb, const float* __restrict__ sybn,
                                const float* __restrict__ lw,  const float* __restrict__ lb,  const float* __restrict__ lbn,
                                const float* __restrict__ x, float* __restrict__ ws) {
    if (blockIdx.x >= 400) {
        int bc = blockIdx.x - 400;
        const float4* p = (const float4*)(x + (size_t)bc * (HH * WW));
        float s = 0.f;
        for (int i = threadIdx.x; i < (HH * WW) / 4; i += 256) {
            float4 v = p[i];
            s += (v.x + v.y) + (v.z + v.w);
        }
        #pragma unroll
        for (int off = 32; off; off >>= 1) s += __shfl_down(s, off, 64);
        __shared__ float red[4];
        int lane = threadIdx.x & 63, w = threadIdx.x >> 6;
        if (lane == 0) red[w] = s;
        __syncthreads();
        if (threadIdx.x == 0)
            ws[WS_GAP + bc] = (red[0] + red[1] + red[2] + red[3]) * (1.f / (HH * WW));
        return;
    }
    int idx = blockIdx.x * 256 + threadIdx.x;
    if (idx < 18432) {  // conv1 A-frags
        int j = idx & 7, lane = (idx >> 3) & 63, oct = (idx >> 9) & 1, ht = idx >> 10;
        int t = ht % 9, h = ht / 9;
        int oc = h * 32 + oct * 16 + (lane & 15);
        int ic = (lane >> 4) * 8 + j;
        float s = mbn1[oc] * rsqrtf(mbn1[192 + oc] + EPS);
        ((unsigned short*)(ws + WS_W1F))[idx] = bf16r(mw1[(oc * IC + ic) * 9 + t] * s);
    }
    if (idx < 102400) {  // conv2 A-frags
        int j = idx & 7, lane = (idx >> 3) & 63, oct = (idx >> 9) & 3, ht = idx >> 11;
        int t = ht % 25, h = ht / 25;
        int oc = oct * 16 + (lane & 15);
        int ic = h * 32 + (lane >> 4) * 8 + j;
        float s = mbn2[oc] * rsqrtf(mbn2[192 + oc] + EPS);
        ((unsigned short*)(ws + WS_W2F))[idx] = bf16r(mw2[(oc * OC + ic) * 25 + t] * s);
    }
    if (idx < 51200) {  // edge-branch fp32 transposed weights [ic][k][oc]
        int oc = idx & 63, k = (idx >> 6) % 25, ic = idx / (25 * 64);
        float ssx = sxbn[oc] * rsqrtf(sxbn[192 + oc] + EPS);
        float ssy = sybn[oc] * rsqrtf(sybn[192 + oc] + EPS);
        float sl  = lbn[oc]  * rsqrtf(lbn[192 + oc]  + EPS);
        ws[WS_SXWT + idx] = sxw[(oc * IC + ic) * 25 + k] * ssx;
        ws[WS_SYWT + idx] = syw[(oc * IC + ic) * 25 + k] * ssy;
        ws[WS_LWT  + idx] = lw [(oc * IC + ic) * 25 + k] * sl;
    }
    if (idx < 64) {
        float s1 = mbn1[idx] * rsqrtf(mbn1[192 + idx] + EPS);
        ws[WS_B1F + idx] = (mb1[idx] - mbn1[128 + idx]) * s1 + mbn1[64 + idx];
        float s2 = mbn2[idx] * rsqrtf(mbn2[192 + idx] + EPS);
        ws[WS_B2F + idx] = (mb2[idx] - mbn2[128 + idx]) * s2 + mbn2[64 + idx];
        float sx = sxbn[idx] * rsqrtf(sxbn[192 + idx] + EPS);
        ws[WS_SXBF + idx] = (sxb[idx] - sxbn[128 + idx]) * sx + sxbn[64 + idx];
        float sy = sybn[idx] * rsqrtf(sybn[192 + idx] + EPS);
        ws[WS_SYBF + idx] = (syb[idx] - sybn[128 + idx]) * sy + sybn[64 + idx];
        float sl = lbn[idx] * rsqrtf(lbn[192 + idx] + EPS);
        ws[WS_LBF + idx] = (lb[idx] - lbn[128 + idx]) * sl + lbn[64 + idx];
    }
}

__global__ void gate_kernel(const float* __restrict__ w1, const float* __restrict__ b1,
                            const float* __restrict__ gbn,
                            const float* __restrict__ w2, const float* __restrict__ b2,
                            float* __restrict__ ws) {
    __shared__ float hsh[8][32];
    int tid = threadIdx.x;
    int b = tid >> 5, j = tid & 31;
    float acc = b1[j];
    for (int i = 0; i < 32; i++) acc += ws[WS_GAP + b * 32 + i] * w1[j * 32 + i];
    float s = gbn[j] * rsqrtf(gbn[96 + j] + EPS);
    hsh[b][j] = tanhf((acc - gbn[64 + j]) * s + gbn[32 + j]);
    __syncthreads();
    if (tid < 8) {
        float best = -1e30f; int bi = 0;
        for (int c = 0; c < 3; c++) {
            float k = b2[c];
            for (int jj = 0; jj < 32; jj++) k += hsh[tid][jj] * w2[c * 32 + jj];
            if (k > best) { best = k; bi = c; }
        }
        ((int*)ws)[WS_BIDX + tid] = bi;
    }
}

// ------------------------------------------------------------------
// xs circular-window addressing (main kernel):
//   storage col sc = abs_col & 31; 32 shorts per (row, sc);
//   16B channel-group g (8 ch) stored at group (g ^ (abs_col & 3)).
//   idx(r, c, g, s) = r*1024 + (c&31)*32 + ((g ^ (c&3))*8) + s
// Conflict-free for conv1 b128 reads (8 accesses/bank uniform).
// stage_cols: stage NBLK aligned 4-col blocks starting at c00 for rows
// ty-3..ty+18, all 32 ic, as transient load->convert->ds_write (no regs
// held across barriers — the R4 spill lesson).
// ------------------------------------------------------------------
template <int NBLK>
__device__ __forceinline__ void stage_cols(const float* __restrict__ xb, short* __restrict__ xs,
                                           int ty, int c00, int tid) {
    constexpr int NUNIT = 22 * NBLK * 16;
    constexpr int NITER = (NUNIT + 255) / 256;
    #pragma unroll
    for (int i = 0; i < NITER; i++) {
        int u = tid + i * 256;
        if (u < NUNIT) {
            int ip = u & 15;
            int blk = (u >> 4) % NBLK;
            int r = (u >> 4) / NBLK;
            int ic = ip * 2, g = ip >> 2, ics = ic & 7;
            int c0 = c00 + blk * 4;
            int gy = ty - 3 + r;
            bool valid = ((unsigned)gy < HH) && ((unsigned)c0 < WW);
            const float* src = xb + (size_t)ic * (HH * WW) + (size_t)(gy & 255) * WW + (c0 & 255);
            float4 fa = valid ? *(const float4*)src : make_float4(0.f, 0.f, 0.f, 0.f);
            float4 fb = valid ? *(const float4*)(src + HH * WW) : make_float4(0.f, 0.f, 0.f, 0.f);
            float ea[4] = {fa.x, fa.y, fa.z, fa.w};
            float eb[4] = {fb.x, fb.y, fb.z, fb.w};
            #pragma unroll
            for (int e = 0; e < 4; e++) {
                int c = c0 + e, sc = c & 31;
                int idx = r * XROW + sc * 32 + ((g ^ (c & 3)) * 8) + ics;
                *(unsigned int*)(xs + idx) =
                    (unsigned int)bf16r(ea[e]) | ((unsigned int)bf16r(eb[e]) << 16);
            }
        }
    }
}

// ------------------------------------------------------------------
// main branch: fused conv3x3+bn+relu -> conv5x5+bn+relu via bf16 MFMA.
// R5: block walks 4 adjacent 16x16 tiles (grid 64 x 8, 2 blk/CU) with an
// LDS circular x-window: per tile only 16 new columns are staged, split
// across the two conv2 (MFMA-heavy) phases; all staging is transient.
//   xs: 22 rows x 32 circ cols x 32 ch bf16, XOR-swizzled (45056 B)
//   ys: [20x20 px][32 half-ch] bf16, stride 40 (32000 B)  -> 77056 B LDS
// MFMA 16x16x32 layouts (m89): A[m=lane&15][k=quad*8+j],
// B[k=quad*8+j][n=lane&15], D: col=lane&15, row=quad*4+reg.
// ------------------------------------------------------------------
__global__ void __launch_bounds__(256, 2)
main_kernel(const float* __restrict__ x, const float* __restrict__ ws, float* __restrict__ out) {
    __shared__ __align__(16) short xs[22 * XROW];
    __shared__ __align__(16) short ys[400 * YSTR];

    int b = blockIdx.y;
    if (((const int*)ws)[WS_BIDX + b] != 0) return;
    int q = blockIdx.x;              // 64 blocks: tile-row = q>>2, colgroup = q&3
    int ty  = (q >> 2) * 16;
    int tx0 = (q & 3) * 64;
    int tid = threadIdx.x;
    int w = tid >> 6, lane = tid & 63, n = lane & 15, quad = lane >> 4;

    const float* xb = x + (size_t)b * IC * HH * WW;
    const short* w1v = (const short*)(ws + WS_W1F);
    const bf16x8* w2v = (const bf16x8*)(ws + WS_W2F);

    // ---- initial stage: cols tx0-4 .. tx0+19 (6 blocks) ----
    stage_cols<6>(xb, xs, ty, tx0 - 4, tid);
    __syncthreads();

    int mrow0 = w * 4;   // conv2 output rows of this wave
    int yr0   = w * 5;   // conv1 output rows of this wave

    #pragma unroll 1
    for (int t = 0; t < 4; t++) {
        int tx = tx0 + t * 16;

        f32x4 acc2[4][4];
        #pragma unroll
        for (int i = 0; i < 4; i++)
            #pragma unroll
            for (int jj = 0; jj < 4; jj++) acc2[i][jj] = (f32x4){0.f, 0.f, 0.f, 0.f};

        #pragma unroll 1
        for (int h = 0; h < 2; h++) {
            // ---- conv1 half h: Y[20x20][32] for conv1 oc = h*32..h*32+31 ----
            #pragma unroll
            for (int cg = 0; cg < 2; cg++) {
                int cb = cg * 4;
                f32x4 a1[5][2];
                #pragma unroll
                for (int rr = 0; rr < 5; rr++) {
                    a1[rr][0] = (f32x4){0.f, 0.f, 0.f, 0.f};
                    a1[rr][1] = (f32x4){0.f, 0.f, 0.f, 0.f};
                }
                #pragma unroll
                for (int dw = 0; dw < 3; dw++) {
                    bf16x8 w1f[3][2];
                    #pragma unroll
                    for (int dh = 0; dh < 3; dh++) {
                        int tt = dh * 3 + dw;
                        w1f[dh][0] = *(const bf16x8*)(w1v + (((h * 9 + tt) * 2 + 0) * 64 + lane) * 8);
                        w1f[dh][1] = *(const bf16x8*)(w1v + (((h * 9 + tt) * 2 + 1) * 64 + lane) * 8);
                    }
                    int cA = tx - 3 + cb + n + dw;
                    int scoff = (cA & 31) * 32 + ((quad ^ (cA & 3)) * 8);
                    bf16x8 bfr[7];
                    #pragma unroll
                    for (int rI = 0; rI < 7; rI++)
                        bfr[rI] = *(const bf16x8*)(xs + (yr0 + rI) * XROW + scoff);
                    #pragma unroll
                    for (int dh = 0; dh < 3; dh++)
                        #pragma unroll
                        for (int rr = 0; rr < 5; rr++) {
                            a1[rr][0] = __builtin_amdgcn_mfma_f32_16x16x32_bf16(w1f[dh][0], bfr[rr + dh], a1[rr][0], 0, 0, 0);
                            a1[rr][1] = __builtin_amdgcn_mfma_f32_16x16x32_bf16(w1f[dh][1], bfr[rr + dh], a1[rr][1], 0, 0, 0);
                        }
                }
                #pragma unroll
                for (int oct = 0; oct < 2; oct++) {
                    float bias1[4];
                    #pragma unroll
                    for (int r = 0; r < 4; r++)
                        bias1[r] = ws[WS_B1F + h * 32 + oct * 16 + quad * 4 + r];
                    #pragma unroll
                    for (int rr = 0; rr < 5; rr++) {
                        int yr = yr0 + rr;
                        int gy2 = ty - 2 + yr, gx2 = tx - 2 + cb + n;
                        bool inb = ((unsigned)gy2 < HH) && ((unsigned)gx2 < WW);
                        float v0 = inb ? fmaxf(a1[rr][oct][0] + bias1[0], 0.f) : 0.f;
                        float v1 = inb ? fmaxf(a1[rr][oct][1] + bias1[1], 0.f) : 0.f;
                        float v2 = inb ? fmaxf(a1[rr][oct][2] + bias1[2], 0.f) : 0.f;
                        float v3 = inb ? fmaxf(a1[rr][oct][3] + bias1[3], 0.f) : 0.f;
                        uint2 pk;
                        pk.x = (unsigned int)bf16r(v0) | ((unsigned int)bf16r(v1) << 16);
                        pk.y = (unsigned int)bf16r(v2) | ((unsigned int)bf16r(v3) << 16);
                        *(uint2*)(ys + (yr * 20 + cb + n) * YSTR + oct * 16 + quad * 4) = pk;
                    }
                }
            }
            __syncthreads();   // ys ready for conv2; conv1's xs reads done

            // stage next tile's new columns during the MFMA-heavy conv2 phase.
            // h0: cols tx+16..27 (aliases tx-16..tx-5: not read by conv1-h1).
            // h1: cols tx+28..35 (no xs readers remain this tile).
            if (t < 3) {
                if (h == 0) stage_cols<3>(xb, xs, ty, tx + 16, tid);
                else        stage_cols<2>(xb, xs, ty, tx + 28, tid);
            }

            // ---- conv2 partial: K-step = this half's 32 channels, 25 taps ----
            const bf16x8* w2h = w2v + (size_t)h * 100 * 64;
            bf16x8 af[4];
            {
                int base = lane;
                af[0] = w2h[base]; af[1] = w2h[base + 64]; af[2] = w2h[base + 128]; af[3] = w2h[base + 192];
            }
            bf16x8 bfr2[8];
            #pragma unroll
            for (int k = 0; k < 25; k++) {
                int dw = k / 5, dh = k % 5;
                if (dh == 0) {
                    #pragma unroll
                    for (int rI = 0; rI < 8; rI++)
                        bfr2[rI] = *(const bf16x8*)(ys + ((mrow0 + rI) * 20 + n + dw) * YSTR + quad * 8);
                }
                bf16x8 an[4];
                if (k < 24) {
                    int kk = k + 1;
                    int tn = (kk % 5) * 5 + (kk / 5);
                    int base = tn * 4 * 64 + lane;
                    an[0] = w2h[base]; an[1] = w2h[base + 64]; an[2] = w2h[base + 128]; an[3] = w2h[base + 192];
                }
                #pragma unroll
                for (int r4 = 0; r4 < 4; r4++) {
                    bf16x8 bb = bfr2[r4 + dh];
                    acc2[r4][0] = __builtin_amdgcn_mfma_f32_16x16x32_bf16(af[0], bb, acc2[r4][0], 0, 0, 0);
                    acc2[r4][1] = __builtin_amdgcn_mfma_f32_16x16x32_bf16(af[1], bb, acc2[r4][1], 0, 0, 0);
                    acc2[r4][2] = __builtin_amdgcn_mfma_f32_16x16x32_bf16(af[2], bb, acc2[r4][2], 0, 0, 0);
                    acc2[r4][3] = __builtin_amdgcn_mfma_f32_16x16x32_bf16(af[3], bb, acc2[r4][3], 0, 0, 0);
                }
                af[0] = an[0]; af[1] = an[1]; af[2] = an[2]; af[3] = an[3];
            }
            if (h == 0) __syncthreads();   // ys rewritten in conv1-h1
        }

        // ---- epilogue: relu(acc + b2f), store tile t ----
        {
            float bias2[4][4];
            #pragma unroll
            for (int oct = 0; oct < 4; oct++)
                #pragma unroll
                for (int r = 0; r < 4; r++)
                    bias2[oct][r] = ws[WS_B2F + oct * 16 + quad * 4 + r];

            float* ob = out + (size_t)b * OC * HH * WW;
            #pragma unroll
            for (int r4 = 0; r4 < 4; r4++) {
                int orow = mrow0 + r4;
                #pragma unroll
                for (int oct = 0; oct < 4; oct++) {
                    #pragma unroll
                    for (int r = 0; r < 4; r++) {
                        int oc = oct * 16 + quad * 4 + r;
                        float v = fmaxf(acc2[r4][oct][r] + bias2[oct][r], 0.f);
                        ob[(size_t)oc * (HH * WW) + (ty + orow) * WW + tx + n] = v;
                    }
                }
            }
        }
        __syncthreads();   // staged xs visible + ys safe for next tile
    }
}

// ------------------------------------------------------------------
// edge branches merged into one kernel (inactive for this seed's gate).
// ------------------------------------------------------------------
template <int KID>
__device__ void edge_body(const float* __restrict__ xb, const float* __restrict__ ws,
                          float* __restrict__ ob, int ty, int tx,
                          float scale, int accumulate, int wt_off, int bf_off,
                          float* __restrict__ xsf, float* __restrict__ ysf) {
    constexpr float KSX[9] = {1, 0, -1, 2, 0, -2, 1, 0, -1};
    constexpr float KSY[9] = {1, 2, 1, 0, 0, 0, -1, -2, -1};
    constexpr float KLP[9] = {0, 1, 0, 1, -4, 1, 0, 1, 0};

    int tid = threadIdx.x;
    const float* wt = ws + wt_off;
    const float* bf = ws + bf_off;

    float acc[8][8];
    #pragma unroll
    for (int o = 0; o < 8; o++)
        #pragma unroll
        for (int j = 0; j < 8; j++) acc[o][j] = 0.f;

    int ocg = tid >> 5;
    int ps  = tid & 31;
    int row = ps >> 1, c0 = (ps & 1) * 8;

    for (int icc = 0; icc < 4; icc++) {
        if (icc) __syncthreads();
        for (int i = tid; i < 8 * 484; i += 256) {
            int ch = i / 484, rem = i % 484, rr = rem / 22, cc = rem % 22;
            int ic = icc * 8 + ch;
            int gy = ty - 3 + rr, gx = tx - 3 + cc;
            float v = 0.f;
            if ((unsigned)gy < HH && (unsigned)gx < WW) v = xb[(size_t)ic * HH * WW + gy * WW + gx];
            xsf[i] = v;
        }
        __syncthreads();
        for (int p = tid; p < 400; p += 256) {
            int r = p / 20, c = p % 20;
            bool inb = ((unsigned)(ty - 2 + r) < HH) && ((unsigned)(tx - 2 + c) < WW);
            #pragma unroll
            for (int ch = 0; ch < 8; ch++) {
                const float* xp = xsf + ch * 484 + r * 22 + c;
                float v = 0.f;
                #pragma unroll
                for (int k = 0; k < 9; k++) {
                    float kv = (KID == 0) ? KSX[k] : (KID == 1) ? KSY[k] : KLP[k];
                    if (kv != 0.f) v += kv * xp[(k / 3) * 22 + (k % 3)];
                }
                ysf[ch * 400 + p] = inb ? v : 0.f;
            }
        }
        __syncthreads();
        for (int ic8 = 0; ic8 < 8; ic8++) {
            const float* yc = ysf + ic8 * 400;
            const float* wbase = wt + ((icc * 8 + ic8) * 25) * 64 + ocg * 8;
            #pragma unroll
            for (int dh = 0; dh < 5; dh++) {
                #pragma unroll
                for (int dw = 0; dw < 5; dw++) {
                    const float* yp = yc + (row + dh) * 20 + c0 + dw;
                    float yv[8];
                    #pragma unroll
                    for (int j = 0; j < 8; j++) yv[j] = yp[j];
                    const float4* wp = (const float4*)(wbase + (dh * 5 + dw) * 64);
                    float4 wa = wp[0], wb = wp[1];
                    float wr[8] = {wa.x, wa.y, wa.z, wa.w, wb.x, wb.y, wb.z, wb.w};
                    #pragma unroll
                    for (int o = 0; o < 8; o++)
                        #pragma unroll
                        for (int j = 0; j < 8; j++) acc[o][j] += wr[o] * yv[j];
                }
            }
        }
    }
    #pragma unroll
    for (int o = 0; o < 8; o++) {
        int oc = ocg * 8 + o;
        float bb = bf[oc];
        float* op = ob + (size_t)oc * HH * WW + (ty + row) * WW + tx + c0;
        if (accumulate) {
            #pragma unroll
            for (int j = 0; j < 8; j++) op[j] += scale * fmaxf(acc[o][j] + bb, 0.f);
        } else {
            #pragma unroll
            for (int j = 0; j < 8; j++) op[j] = scale * fmaxf(acc[o][j] + bb, 0.f);
        }
    }
}

__global__ void __launch_bounds__(256, 2)
edge_kernel_all(const float* __restrict__ x, const float* __restrict__ ws, float* __restrict__ out) {
    __shared__ float xsf[8 * 484];
    __shared__ float ysf[8 * 400];
    int b = blockIdx.y;
    int bi = ((const int*)ws)[WS_BIDX + b];
    if (bi == 0) return;
    int tile = blockIdx.x;
    int ty = (tile >> 4) * 16, tx = (tile & 15) * 16;
    const float* xb = x + (size_t)b * IC * HH * WW;
    float* ob = out + (size_t)b * OC * HH * WW;
    if (bi == 1) {
        edge_body<0>(xb, ws, ob, ty, tx, 0.5f, 0, WS_SXWT, WS_SXBF, xsf, ysf);
        __syncthreads();
        edge_body<1>(xb, ws, ob, ty, tx, 0.5f, 1, WS_SYWT, WS_SYBF, xsf, ysf);
    } else {
        edge_body<2>(xb, ws, ob, ty, tx, 1.0f, 0, WS_LWT, WS_LBF, xsf, ysf);
    }
}

// ------------------------------------------------------------------
extern "C" void kernel_launch(void* const* d_in, const int* in_sizes, int n_in,
                              void* d_out, int out_size, void* d_ws, size_t ws_size,
                              hipStream_t stream) {
    const float* x    = (const float*)d_in[0];
    const float* gw1  = (const float*)d_in[1];
    const float* gb1  = (const float*)d_in[2];
    const float* gbn  = (const float*)d_in[3];
    const float* gw2  = (const float*)d_in[4];
    const float* gb2  = (const float*)d_in[5];
    const float* mw1  = (const float*)d_in[6];
    const float* mb1  = (const float*)d_in[7];
    const float* mbn1 = (const float*)d_in[8];
    const float* mw2  = (const float*)d_in[9];
    const float* mb2  = (const float*)d_in[10];
    const float* mbn2 = (const float*)d_in[11];
    const float* sxw  = (const float*)d_in[12];
    const float* sxb  = (const float*)d_in[13];
    const float* sxbn = (const float*)d_in[14];
    const float* syw  = (const float*)d_in[15];
    const float* syb  = (const float*)d_in[16];
    const float* sybn = (const float*)d_in[17];
    const float* lw   = (const float*)d_in[18];
    const float* lb   = (const float*)d_in[19];
    const float* lbn  = (const float*)d_in[20];
    float* ws  = (float*)d_ws;
    float* out = (float*)d_out;

    prep_gap_kernel<<<656, 256, 0, stream>>>(mw1, mb1, mbn1, mw2, mb2, mbn2,
                                             sxw, sxb, sxbn, syw, syb, sybn, lw, lb, lbn,
                                             x, ws);
    gate_kernel<<<1, 256, 0, stream>>>(gw1, gb1, gbn, gw2, gb2, ws);

    dim3 grid_main(64, BB);
    main_kernel<<<grid_main, 256, 0, stream>>>(x, ws, out);
    dim3 grid_edge(256, BB);
    edge_kernel_all<<<grid_edge, 256, 0, stream>>>(x, ws, out);
}